// Round 14
// baseline (313.676 us; speedup 1.0000x reference)
//
#include <hip/hip_runtime.h>
#include <math.h>

#define NUM_E   1024
#define ZQ_ELEM 8388608         // 32*64*64*64
#define AGRID   1024
#define QCAP    2048

typedef short bf16x8 __attribute__((ext_vector_type(8)));
typedef float f32x16 __attribute__((ext_vector_type(16)));

__device__ inline unsigned short rne_bf16(float v) {
    unsigned u = __float_as_uint(v);
    return (unsigned short)((u + 0x7FFFu + ((u >> 16) & 1u)) >> 16);  // RNE, finite-safe
}

// ---------------------------------------------------------------- prep: ee + bf16-hi B fragments
// B-frag layout for mfma_f32_32x32x16_bf16: lane l holds col j = nt*32+(l&31),
// k = kt*16 + (l>>5)*8 + i.  Packet index = (nt*4+kt)*64 + (l>>5)*32 + (j&31).
__global__ __launch_bounds__(256) void vq_prep(const float* __restrict__ cb,
                                               float* __restrict__ ee,
                                               unsigned short* __restrict__ ehi)
{
    int j = blockIdx.x * 256 + threadIdx.x;   // grid 4 -> 1024 codes
    const float* r = cb + (size_t)j * 64;
    float v[64];
#pragma unroll
    for (int k = 0; k < 64; ++k) v[k] = r[k];
    float a = 0.f;
#pragma unroll
    for (int k = 0; k < 64; ++k) a = fmaf(v[k], v[k], a);   // same chain as r1-r13
    ee[j] = a;

    int nt = j >> 5, jc = j & 31;
#pragma unroll
    for (int kt = 0; kt < 4; ++kt)
#pragma unroll
        for (int h = 0; h < 2; ++h) {
            bf16x8 vh;
#pragma unroll
            for (int i = 0; i < 8; ++i)
                vh[i] = (short)rne_bf16(v[kt * 16 + h * 8 + i]);
            *(bf16x8*)(ehi + ((size_t)(nt * 4 + kt) * 64 + h * 32 + jc) * 8) = vh;
        }
}

// exact d for (point pl, code j), z from global, batched loads; fmaf chain order
// bit-identical to the r1-r13 passing formula.
__device__ inline unsigned long long key_glob(const float* zb, float zz, float eej,
                                              const float* cb, int pl, int j)
{
    const float4* cr = (const float4*)(cb + ((size_t)j << 6));
    float a = 0.f;
#pragma unroll
    for (int qb = 0; qb < 4; ++qb) {
        float4 c0 = cr[qb * 4 + 0];
        float4 c1 = cr[qb * 4 + 1];
        float4 c2 = cr[qb * 4 + 2];
        float4 c3 = cr[qb * 4 + 3];
        float t[16];
#pragma unroll
        for (int i = 0; i < 16; ++i)
            t[i] = zb[(size_t)(qb * 16 + i) * 4096 + pl];
        a = fmaf(t[0],  c0.x, a); a = fmaf(t[1],  c0.y, a);
        a = fmaf(t[2],  c0.z, a); a = fmaf(t[3],  c0.w, a);
        a = fmaf(t[4],  c1.x, a); a = fmaf(t[5],  c1.y, a);
        a = fmaf(t[6],  c1.z, a); a = fmaf(t[7],  c1.w, a);
        a = fmaf(t[8],  c2.x, a); a = fmaf(t[9],  c2.y, a);
        a = fmaf(t[10], c2.z, a); a = fmaf(t[11], c2.w, a);
        a = fmaf(t[12], c3.x, a); a = fmaf(t[13], c3.y, a);
        a = fmaf(t[14], c3.z, a); a = fmaf(t[15], c3.w, a);
    }
    float t1 = zz + eej;
    float d  = fmaf(-2.f, a, t1);
    return ((unsigned long long)__float_as_uint(d) << 32) | (unsigned long long)j;
}

#define LOADB(H, EV, ntv) do {                                      \
    int _b = (ntv) * 4 * 64 + lane;                                 \
    _Pragma("unroll")                                               \
    for (int _k = 0; _k < 4; ++_k) H[_k] = eh8[_b + _k * 64];       \
    EV = ee[(ntv) * 32 + (lane & 31)];                              \
} while (0)

// split accumulators: two independent 2-deep MFMA chains (ILP), summed once.
// Extra fp32 add rounding <= 4e-9, absorbed by the 1.4e-4 window margin.
#define SW1(H, EV) do {                                             \
    f32x16 _aA, _aB;                                                \
    _Pragma("unroll")                                               \
    for (int _r = 0; _r < 16; ++_r) { _aA[_r] = 0.f; _aB[_r] = 0.f; } \
    _aA = __builtin_amdgcn_mfma_f32_32x32x16_bf16(ah[0], H[0], _aA, 0, 0, 0); \
    _aB = __builtin_amdgcn_mfma_f32_32x32x16_bf16(ah[2], H[2], _aB, 0, 0, 0); \
    _aA = __builtin_amdgcn_mfma_f32_32x32x16_bf16(ah[1], H[1], _aA, 0, 0, 0); \
    _aB = __builtin_amdgcn_mfma_f32_32x32x16_bf16(ah[3], H[3], _aB, 0, 0, 0); \
    _Pragma("unroll")                                               \
    for (int _r = 0; _r < 16; ++_r)                                 \
        m[_r] = fminf(m[_r], fmaf(-2.f, _aA[_r] + _aB[_r], EV));    \
} while (0)

#define ENQ(PL, JJ) do {                                            \
    unsigned _s = atomicAdd(&qcnt, 1u);                             \
    if (_s < QCAP) queue[_s] = ((unsigned)(PL) << 16) | (JJ);       \
    else oflow = 1;                                                 \
} while (0)

#define SW2(H, EV, NTV) do {                                        \
    f32x16 _aA, _aB;                                                \
    _Pragma("unroll")                                               \
    for (int _r = 0; _r < 16; ++_r) { _aA[_r] = 0.f; _aB[_r] = 0.f; } \
    _aA = __builtin_amdgcn_mfma_f32_32x32x16_bf16(ah[0], H[0], _aA, 0, 0, 0); \
    _aB = __builtin_amdgcn_mfma_f32_32x32x16_bf16(ah[2], H[2], _aB, 0, 0, 0); \
    _aA = __builtin_amdgcn_mfma_f32_32x32x16_bf16(ah[1], H[1], _aA, 0, 0, 0); \
    _aB = __builtin_amdgcn_mfma_f32_32x32x16_bf16(ah[3], H[3], _aB, 0, 0, 0); \
    unsigned jj = (unsigned)((NTV) * 32 + (lane & 31));             \
    _Pragma("unroll")                                               \
    for (int _r = 0; _r < 16; ++_r) {                               \
        bool hit = fmaf(-2.f, _aA[_r] + _aB[_r], EV) <= m[_r];      \
        if (__any(hit)) {                                           \
            if (hit) {                                              \
                int pl = wv * 32 + 4 * (lane >> 5) + (_r & 3) + 8 * (_r >> 2); \
                ENQ(pl, jj);                                        \
            }                                                       \
        }                                                           \
    }                                                               \
} while (0)

// ---------------------------------------------------------------- argmin + quant (fused)
// Block = 128 points (2 h-rows), 256 threads = 4 waves; wave wv owns rows wv*32..+31.
// r8 structure + split-acc MFMA ILP + depth-3 B prefetch (4 reg buffer sets).
__global__ __launch_bounds__(256, 3) void vq_argmin(
    const float* __restrict__ z, const float* __restrict__ cb,
    const unsigned short* __restrict__ ehi, const float* __restrict__ ee,
    float* __restrict__ idx_f, int* __restrict__ counts,
    float* __restrict__ zq, double* __restrict__ partials)
{
    __shared__ float zzs[128];
    __shared__ float wp[128];                  // per-point rigorous window
    __shared__ unsigned long long best[128];
    __shared__ unsigned int queue[QCAP];       // 8 KB: (pl<<16)|j
    __shared__ unsigned int qcnt;
    __shared__ unsigned int oflow;
    __shared__ int ibuf[128];
    __shared__ double wsum[4];

    const int tid  = threadIdx.x;
    const int g    = blockIdx.x;               // 1024 blocks: (b, h-pair)
    const int lane = tid & 63, wv = tid >> 6;
    const size_t zoff = ((size_t)(g >> 5) << 18) + (size_t)((g & 31) << 7);
    const float* zb = z + zoff;
    const bf16x8* eh8 = (const bf16x8*)ehi;

    if (tid < 128) best[tid] = 0xFFFFFFFFFFFFFFFFull;
    if (tid == 0) { qcnt = 0; oflow = 0; }

    // ---- zz: exact 64-chain fmaf order (r1-r13), loads batched 16-wide
    if (tid < 128) {
        float a = 0.f;
#pragma unroll
        for (int kb = 0; kb < 4; ++kb) {
            float t[16];
#pragma unroll
            for (int i = 0; i < 16; ++i)
                t[i] = zb[(size_t)(kb * 16 + i) * 4096 + tid];
#pragma unroll
            for (int i = 0; i < 16; ++i) a = fmaf(t[i], t[i], a);
        }
        zzs[tid] = a;
    }

    // ---- A-fragment (z-hi) + per-point rigorous window (r6-r12 formula), batched loads
    bf16x8 ah[4];
    {
        int h = lane >> 5;
        int pl = wv * 32 + (lane & 31);
        float s1 = 0.f, sd = 0.f;
#pragma unroll
        for (int kt = 0; kt < 4; ++kt) {
            float t[8];
#pragma unroll
            for (int i = 0; i < 8; ++i)
                t[i] = zb[(size_t)(kt * 16 + h * 8 + i) * 4096 + pl];
#pragma unroll
            for (int i = 0; i < 8; ++i) {
                float x = t[i];
                unsigned short hb = rne_bf16(x);
                float hf = __uint_as_float((unsigned)hb << 16);
                ah[kt][i] = (short)hb;
                s1 += fabsf(x);
                sd += fabsf(x - hf);
            }
        }
        s1 += __shfl_xor(s1, 32);
        sd += __shfl_xor(sd, 32);
        // W = 2*eps_data bound (x2 margin) + 4e-5 (d<->s offsets) + 1e-4 margin
        if (lane < 32) wp[pl] = 4.f * (s1 * 1.907e-6f + sd * 9.785e-4f) + 1.4e-4f;
    }
    __syncthreads();                           // zzs/wp visible block-wide

    float m[16];
#pragma unroll
    for (int r = 0; r < 16; ++r) m[r] = 3.4e38f;

    // ---- sweep 1: per-row min of s~ (barrier-free, depth-3 rotating prefetch)
    {
        bf16x8 b0[4], b1[4], b2[4], b3[4];
        float e0, e1, e2, e3;
        LOADB(b0, e0, 0); LOADB(b1, e1, 1); LOADB(b2, e2, 2);
#pragma unroll 1
        for (int nt = 0; nt < 32; nt += 4) {
            LOADB(b3, e3, nt + 3);
            SW1(b0, e0);
            if (nt + 4 < 32) LOADB(b0, e0, nt + 4);
            SW1(b1, e1);
            if (nt + 5 < 32) LOADB(b1, e1, nt + 5);
            SW1(b2, e2);
            if (nt + 6 < 32) LOADB(b2, e2, nt + 6);
            SW1(b3, e3);
        }
    }
    // butterfly min across 32 col-lanes, then fold per-point window -> threshold
#pragma unroll
    for (int r = 0; r < 16; ++r) {
        for (int d2 = 1; d2 <= 16; d2 <<= 1)
            m[r] = fminf(m[r], __shfl_xor(m[r], d2));
        m[r] += wp[wv * 32 + 4 * (lane >> 5) + (r & 3) + 8 * (r >> 2)];
    }

    // ---- sweep 2: recompute (identical formula), enqueue window hits
    {
        bf16x8 b0[4], b1[4], b2[4], b3[4];
        float e0, e1, e2, e3;
        LOADB(b0, e0, 0); LOADB(b1, e1, 1); LOADB(b2, e2, 2);
#pragma unroll 1
        for (int nt = 0; nt < 32; nt += 4) {
            LOADB(b3, e3, nt + 3);
            SW2(b0, e0, nt);
            if (nt + 4 < 32) LOADB(b0, e0, nt + 4);
            SW2(b1, e1, nt + 1);
            if (nt + 5 < 32) LOADB(b1, e1, nt + 5);
            SW2(b2, e2, nt + 2);
            if (nt + 6 < 32) LOADB(b2, e2, nt + 6);
            SW2(b3, e3, nt + 3);
        }
    }
    __syncthreads();

    // ---- exact refine (expected ~175 candidates; oflow = never-taken safety net)
    if (oflow) {
        if (tid < 128) {
            unsigned long long bk = 0xFFFFFFFFFFFFFFFFull;
            for (int j = 0; j < NUM_E; ++j) {
                unsigned long long k2 = key_glob(zb, zzs[tid], ee[j], cb, tid, j);
                if (k2 < bk) bk = k2;
            }
            best[tid] = bk;
        }
    } else {
        int nq = (int)qcnt;
        for (int e = tid; e < nq; e += 256) {
            unsigned u = queue[e];
            int pl = (int)(u >> 16), j = (int)(u & 0xFFFFu);
            atomicMin(&best[pl], key_glob(zb, zzs[pl], ee[j], cb, pl, j));
        }
    }
    __syncthreads();
    if (tid < 128) {
        int bi = (int)(best[tid] & 0xFFFFFFFFull);
        ibuf[tid] = bi;
        idx_f[(size_t)g * 128 + tid] = (float)bi;
        atomicAdd(&counts[bi], 1);
    }
    __syncthreads();

    // ---- fused tail: z_q_st = fl(z + fl(q - z)); preloaded z float4s, float4 stores
    {
        int w4 = tid & 31, c8 = (tid >> 5) * 8;
        const float4* zb4 = (const float4*)zb;
        float4* zq4 = (float4*)(zq + zoff);
        size_t b0 = (size_t)ibuf[w4 * 4 + 0] << 6;
        size_t b1 = (size_t)ibuf[w4 * 4 + 1] << 6;
        size_t b2 = (size_t)ibuf[w4 * 4 + 2] << 6;
        size_t b3 = (size_t)ibuf[w4 * 4 + 3] << 6;
        float4 zv[8];
#pragma unroll
        for (int i = 0; i < 8; ++i) zv[i] = zb4[(size_t)(c8 + i) * 1024 + w4];
        double ls = 0.0;
#pragma unroll
        for (int i = 0; i < 8; ++i) {
            int c = c8 + i;
            float q0 = cb[b0 + c], q1 = cb[b1 + c], q2 = cb[b2 + c], q3 = cb[b3 + c];
            float t0 = q0 - zv[i].x, t1 = q1 - zv[i].y, t2 = q2 - zv[i].z, t3 = q3 - zv[i].w;
            zq4[(size_t)c * 1024 + w4] =
                make_float4(zv[i].x + t0, zv[i].y + t1, zv[i].z + t2, zv[i].w + t3);
            ls += (double)t0 * t0 + (double)t1 * t1 + (double)t2 * t2 + (double)t3 * t3;
        }
#pragma unroll
        for (int off = 32; off > 0; off >>= 1) ls += __shfl_down(ls, off);
        if ((tid & 63) == 0) wsum[tid >> 6] = ls;
    }
    __syncthreads();
    if (tid == 0) partials[g] = wsum[0] + wsum[1] + wsum[2] + wsum[3];
}

// ---------------------------------------------------------------- scalars
__global__ __launch_bounds__(256) void vq_final(
    const int* __restrict__ counts, const double* __restrict__ partials,
    float* __restrict__ scalars)
{
    __shared__ double sh[256];
    __shared__ double sl[256];
    int t = threadIdx.x;
    double s = 0.0;
    for (int j = t; j < NUM_E; j += 256) {
        float em   = (float)counts[j] * (1.0f / 131072.0f);
        float term = em * logf(em + 1e-10f);
        s += (double)term;
    }
    double l = 0.0;
#pragma unroll
    for (int j = 0; j < AGRID / 256; ++j) l += partials[j * 256 + t];
    sh[t] = s;
    sl[t] = l;
    __syncthreads();
    for (int off = 128; off > 0; off >>= 1) {
        if (t < off) { sh[t] += sh[t + off]; sl[t] += sl[t + off]; }
        __syncthreads();
    }
    if (t == 0) {
        float mm = (float)(sl[0] / 8388608.0);
        scalars[0] = mm + 0.5f * mm;         // mean1 + BETA*mean2
        scalars[1] = expf(-(float)sh[0]);    // perplexity
    }
}

// ---------------------------------------------------------------- launch
extern "C" void kernel_launch(void* const* d_in, const int* in_sizes, int n_in,
                              void* d_out, int out_size, void* d_ws, size_t ws_size,
                              hipStream_t stream)
{
    const float* z  = (const float*)d_in[0];
    const float* cb = (const float*)d_in[1];
    float* out     = (float*)d_out;
    float* zq      = out;                    // [32,64,64,64]
    float* scalars = out + ZQ_ELEM;          // loss, perplexity
    float* idx_f   = out + ZQ_ELEM + 2;      // [32,64,64] as float

    int*            counts   = (int*)d_ws;                             // 4 KB
    double*         partials = (double*)((char*)d_ws + 4096);          // 8 KB
    float*          ee       = (float*)((char*)d_ws + 12288);          // 4 KB
    unsigned short* ehi      = (unsigned short*)((char*)d_ws + 16384); // 128 KB

    hipMemsetAsync(d_ws, 0, 4096, stream);                    // zero counts
    vq_prep  <<<4,     256, 0, stream>>>(cb, ee, ehi);
    vq_argmin<<<AGRID, 256, 0, stream>>>(z, cb, ehi, ee, idx_f, counts, zq, partials);
    vq_final <<<1,     256, 0, stream>>>(counts, partials, scalars);
}

// Round 15
// 201.191 us; speedup vs baseline: 1.5591x; 1.5591x over previous
//
#include <hip/hip_runtime.h>
#include <math.h>

#define NUM_E   1024
#define ZQ_ELEM 8388608         // 32*64*64*64
#define AGRID   1024
#define QCAP    3072

typedef short bf16x8 __attribute__((ext_vector_type(8)));
typedef float f32x16 __attribute__((ext_vector_type(16)));

__device__ inline unsigned short rne_bf16(float v) {
    unsigned u = __float_as_uint(v);
    return (unsigned short)((u + 0x7FFFu + ((u >> 16) & 1u)) >> 16);  // RNE, finite-safe
}

// ---------------------------------------------------------------- prep: ee + bf16-hi B fragments
// B-frag layout for mfma_f32_32x32x16_bf16: lane l holds col j = nt*32+(l&31),
// k = kt*16 + (l>>5)*8 + i.  Packet index = (nt*4+kt)*64 + (l>>5)*32 + (j&31).
__global__ __launch_bounds__(256) void vq_prep(const float* __restrict__ cb,
                                               float* __restrict__ ee,
                                               unsigned short* __restrict__ ehi)
{
    int j = blockIdx.x * 256 + threadIdx.x;   // grid 4 -> 1024 codes
    const float* r = cb + (size_t)j * 64;
    float v[64];
#pragma unroll
    for (int k = 0; k < 64; ++k) v[k] = r[k];
    float a = 0.f;
#pragma unroll
    for (int k = 0; k < 64; ++k) a = fmaf(v[k], v[k], a);   // same chain as r1-r14
    ee[j] = a;

    int nt = j >> 5, jc = j & 31;
#pragma unroll
    for (int kt = 0; kt < 4; ++kt)
#pragma unroll
        for (int h = 0; h < 2; ++h) {
            bf16x8 vh;
#pragma unroll
            for (int i = 0; i < 8; ++i)
                vh[i] = (short)rne_bf16(v[kt * 16 + h * 8 + i]);
            *(bf16x8*)(ehi + ((size_t)(nt * 4 + kt) * 64 + h * 32 + jc) * 8) = vh;
        }
}

// exact d for (point pl, code j), z from global, batched loads; fmaf chain order
// bit-identical to the r1-r14 passing formula.
__device__ inline unsigned long long key_glob(const float* zb, float zz, float eej,
                                              const float* cb, int pl, int j)
{
    const float4* cr = (const float4*)(cb + ((size_t)j << 6));
    float a = 0.f;
#pragma unroll
    for (int qb = 0; qb < 4; ++qb) {
        float4 c0 = cr[qb * 4 + 0];
        float4 c1 = cr[qb * 4 + 1];
        float4 c2 = cr[qb * 4 + 2];
        float4 c3 = cr[qb * 4 + 3];
        float t[16];
#pragma unroll
        for (int i = 0; i < 16; ++i)
            t[i] = zb[(size_t)(qb * 16 + i) * 4096 + pl];
        a = fmaf(t[0],  c0.x, a); a = fmaf(t[1],  c0.y, a);
        a = fmaf(t[2],  c0.z, a); a = fmaf(t[3],  c0.w, a);
        a = fmaf(t[4],  c1.x, a); a = fmaf(t[5],  c1.y, a);
        a = fmaf(t[6],  c1.z, a); a = fmaf(t[7],  c1.w, a);
        a = fmaf(t[8],  c2.x, a); a = fmaf(t[9],  c2.y, a);
        a = fmaf(t[10], c2.z, a); a = fmaf(t[11], c2.w, a);
        a = fmaf(t[12], c3.x, a); a = fmaf(t[13], c3.y, a);
        a = fmaf(t[14], c3.z, a); a = fmaf(t[15], c3.w, a);
    }
    float t1 = zz + eej;
    float d  = fmaf(-2.f, a, t1);
    return ((unsigned long long)__float_as_uint(d) << 32) | (unsigned long long)j;
}

#define LOADB(H, EV, ntv) do {                                      \
    int _b = (ntv) * 4 * 64 + lane;                                 \
    _Pragma("unroll")                                               \
    for (int _k = 0; _k < 4; ++_k) H[_k] = eh8[_b + _k * 64];       \
    EV = ee[(ntv) * 32 + (lane & 31)];                              \
} while (0)

// r8's chained 4-MFMA (no split acc -- r14's spilled), min-only (warm pass)
#define SWMIN(H, EV) do {                                           \
    f32x16 _ac;                                                     \
    _Pragma("unroll")                                               \
    for (int _r = 0; _r < 16; ++_r) _ac[_r] = 0.f;                  \
    _ac = __builtin_amdgcn_mfma_f32_32x32x16_bf16(ah[0], H[0], _ac, 0, 0, 0); \
    _ac = __builtin_amdgcn_mfma_f32_32x32x16_bf16(ah[1], H[1], _ac, 0, 0, 0); \
    _ac = __builtin_amdgcn_mfma_f32_32x32x16_bf16(ah[2], H[2], _ac, 0, 0, 0); \
    _ac = __builtin_amdgcn_mfma_f32_32x32x16_bf16(ah[3], H[3], _ac, 0, 0, 0); \
    _Pragma("unroll")                                               \
    for (int _r = 0; _r < 16; ++_r)                                 \
        m[_r] = fminf(m[_r], fmaf(-2.f, _ac[_r], EV));              \
} while (0)

#define ENQ(PL, JJ) do {                                            \
    unsigned _s = atomicAdd(&qcnt, 1u);                             \
    if (_s < QCAP) queue[_s] = ((unsigned)(PL) << 16) | (JJ);       \
    else oflow = 1;                                                 \
} while (0)

// enqueue pass: identical MFMA/s~ arithmetic; test vs running min + wp, then update min
#define SWENQ(H, EV, NTV) do {                                      \
    f32x16 _ac;                                                     \
    _Pragma("unroll")                                               \
    for (int _r = 0; _r < 16; ++_r) _ac[_r] = 0.f;                  \
    _ac = __builtin_amdgcn_mfma_f32_32x32x16_bf16(ah[0], H[0], _ac, 0, 0, 0); \
    _ac = __builtin_amdgcn_mfma_f32_32x32x16_bf16(ah[1], H[1], _ac, 0, 0, 0); \
    _ac = __builtin_amdgcn_mfma_f32_32x32x16_bf16(ah[2], H[2], _ac, 0, 0, 0); \
    _ac = __builtin_amdgcn_mfma_f32_32x32x16_bf16(ah[3], H[3], _ac, 0, 0, 0); \
    unsigned jj = (unsigned)((NTV) * 32 + (lane & 31));             \
    _Pragma("unroll")                                               \
    for (int _r = 0; _r < 16; ++_r) {                               \
        float _s = fmaf(-2.f, _ac[_r], EV);                         \
        bool hit = _s <= m[_r] + wpr[_r];                           \
        m[_r] = fminf(m[_r], _s);                                   \
        if (__any(hit)) {                                           \
            if (hit) {                                              \
                int pl = wv * 32 + 4 * (lane >> 5) + (_r & 3) + 8 * (_r >> 2); \
                ENQ(pl, jj);                                        \
            }                                                       \
        }                                                           \
    }                                                               \
} while (0)

// ---------------------------------------------------------------- argmin + quant (fused)
// Block = 128 points (2 h-rows), 256 threads = 4 waves; wave wv owns rows wv*32..+31.
// SINGLE 1.125-pass B stream: warm min (nt 0..3) + one full enqueue pass vs running min.
__global__ __launch_bounds__(256, 4) void vq_argmin(
    const float* __restrict__ z, const float* __restrict__ cb,
    const unsigned short* __restrict__ ehi, const float* __restrict__ ee,
    float* __restrict__ idx_f, int* __restrict__ counts,
    float* __restrict__ zq, double* __restrict__ partials)
{
    __shared__ float zzs[128];
    __shared__ float wp[128];                  // per-point rigorous window
    __shared__ unsigned long long best[128];
    __shared__ unsigned int queue[QCAP];       // 12 KB: (pl<<16)|j
    __shared__ unsigned int qcnt;
    __shared__ unsigned int oflow;
    __shared__ int ibuf[128];
    __shared__ double wsum[4];

    const int tid  = threadIdx.x;
    const int g    = blockIdx.x;               // 1024 blocks: (b, h-pair)
    const int lane = tid & 63, wv = tid >> 6;
    const size_t zoff = ((size_t)(g >> 5) << 18) + (size_t)((g & 31) << 7);
    const float* zb = z + zoff;
    const bf16x8* eh8 = (const bf16x8*)ehi;

    if (tid < 128) best[tid] = 0xFFFFFFFFFFFFFFFFull;
    if (tid == 0) { qcnt = 0; oflow = 0; }

    // ---- zz: exact 64-chain fmaf order (r1-r14), loads batched 16-wide
    if (tid < 128) {
        float a = 0.f;
#pragma unroll
        for (int kb = 0; kb < 4; ++kb) {
            float t[16];
#pragma unroll
            for (int i = 0; i < 16; ++i)
                t[i] = zb[(size_t)(kb * 16 + i) * 4096 + tid];
#pragma unroll
            for (int i = 0; i < 16; ++i) a = fmaf(t[i], t[i], a);
        }
        zzs[tid] = a;
    }

    // ---- A-fragment (z-hi) + per-point rigorous window (r6-r14 formula), batched loads
    bf16x8 ah[4];
    {
        int h = lane >> 5;
        int pl = wv * 32 + (lane & 31);
        float s1 = 0.f, sd = 0.f;
#pragma unroll
        for (int kt = 0; kt < 4; ++kt) {
            float t[8];
#pragma unroll
            for (int i = 0; i < 8; ++i)
                t[i] = zb[(size_t)(kt * 16 + h * 8 + i) * 4096 + pl];
#pragma unroll
            for (int i = 0; i < 8; ++i) {
                float x = t[i];
                unsigned short hb = rne_bf16(x);
                float hf = __uint_as_float((unsigned)hb << 16);
                ah[kt][i] = (short)hb;
                s1 += fabsf(x);
                sd += fabsf(x - hf);
            }
        }
        s1 += __shfl_xor(s1, 32);
        sd += __shfl_xor(sd, 32);
        // W = 2*eps_data bound (x2 margin) + 4e-5 (d<->s offsets) + 1e-4 margin
        if (lane < 32) wp[pl] = 4.f * (s1 * 1.907e-6f + sd * 9.785e-4f) + 1.4e-4f;
    }
    __syncthreads();                           // zzs/wp visible block-wide

    float m[16];
#pragma unroll
    for (int r = 0; r < 16; ++r) m[r] = 3.4e38f;

    // ---- warm pass: row min over nt 0..3 (12.5% of stream), ping-pong
    {
        bf16x8 hA[4], hB[4];
        float eA, eB;
        LOADB(hA, eA, 0);
#pragma unroll 1
        for (int nt = 0; nt < 4; nt += 2) {
            LOADB(hB, eB, nt + 1);
            SWMIN(hA, eA);
            if (nt + 2 < 4) LOADB(hA, eA, nt + 2);
            SWMIN(hB, eB);
        }
    }
    // butterfly min across 32 col-lanes -> strong warm start in every lane
#pragma unroll
    for (int r = 0; r < 16; ++r)
        for (int d2 = 1; d2 <= 16; d2 <<= 1)
            m[r] = fminf(m[r], __shfl_xor(m[r], d2));

    // per-row window into registers
    float wpr[16];
#pragma unroll
    for (int r = 0; r < 16; ++r)
        wpr[r] = wp[wv * 32 + 4 * (lane >> 5) + (r & 3) + 8 * (r >> 2)];

    // ---- single full pass: enqueue all j with s~ <= running_min + wp
    // (true argmin + all exact-ties provably enqueued: s~(j*) <= run_min(t)+wp forall t)
    {
        bf16x8 hA[4], hB[4];
        float eA, eB;
        LOADB(hA, eA, 0);
#pragma unroll 1
        for (int nt = 0; nt < 32; nt += 2) {
            LOADB(hB, eB, nt + 1);
            SWENQ(hA, eA, nt);
            if (nt + 2 < 32) LOADB(hA, eA, nt + 2);
            SWENQ(hB, eB, nt + 1);
        }
    }
    __syncthreads();

    // ---- exact refine of queued candidates (expected ~1000; oflow = safety net)
    if (oflow) {
        if (tid < 128) {
            unsigned long long bk = 0xFFFFFFFFFFFFFFFFull;
            for (int j = 0; j < NUM_E; ++j) {
                unsigned long long k2 = key_glob(zb, zzs[tid], ee[j], cb, tid, j);
                if (k2 < bk) bk = k2;
            }
            best[tid] = bk;
        }
    } else {
        int nq = (int)qcnt;
        for (int e = tid; e < nq; e += 256) {
            unsigned u = queue[e];
            int pl = (int)(u >> 16), j = (int)(u & 0xFFFFu);
            atomicMin(&best[pl], key_glob(zb, zzs[pl], ee[j], cb, pl, j));
        }
    }
    __syncthreads();
    if (tid < 128) {
        int bi = (int)(best[tid] & 0xFFFFFFFFull);
        ibuf[tid] = bi;
        idx_f[(size_t)g * 128 + tid] = (float)bi;
        atomicAdd(&counts[bi], 1);
    }
    __syncthreads();

    // ---- fused tail: z_q_st = fl(z + fl(q - z)); preloaded z float4s, float4 stores
    {
        int w4 = tid & 31, c8 = (tid >> 5) * 8;
        const float4* zb4 = (const float4*)zb;
        float4* zq4 = (float4*)(zq + zoff);
        size_t b0 = (size_t)ibuf[w4 * 4 + 0] << 6;
        size_t b1 = (size_t)ibuf[w4 * 4 + 1] << 6;
        size_t b2 = (size_t)ibuf[w4 * 4 + 2] << 6;
        size_t b3 = (size_t)ibuf[w4 * 4 + 3] << 6;
        float4 zv[8];
#pragma unroll
        for (int i = 0; i < 8; ++i) zv[i] = zb4[(size_t)(c8 + i) * 1024 + w4];
        double ls = 0.0;
#pragma unroll
        for (int i = 0; i < 8; ++i) {
            int c = c8 + i;
            float q0 = cb[b0 + c], q1 = cb[b1 + c], q2 = cb[b2 + c], q3 = cb[b3 + c];
            float t0 = q0 - zv[i].x, t1 = q1 - zv[i].y, t2 = q2 - zv[i].z, t3 = q3 - zv[i].w;
            zq4[(size_t)c * 1024 + w4] =
                make_float4(zv[i].x + t0, zv[i].y + t1, zv[i].z + t2, zv[i].w + t3);
            ls += (double)t0 * t0 + (double)t1 * t1 + (double)t2 * t2 + (double)t3 * t3;
        }
#pragma unroll
        for (int off = 32; off > 0; off >>= 1) ls += __shfl_down(ls, off);
        if ((tid & 63) == 0) wsum[tid >> 6] = ls;
    }
    __syncthreads();
    if (tid == 0) partials[g] = wsum[0] + wsum[1] + wsum[2] + wsum[3];
}

// ---------------------------------------------------------------- scalars
__global__ __launch_bounds__(256) void vq_final(
    const int* __restrict__ counts, const double* __restrict__ partials,
    float* __restrict__ scalars)
{
    __shared__ double sh[256];
    __shared__ double sl[256];
    int t = threadIdx.x;
    double s = 0.0;
    for (int j = t; j < NUM_E; j += 256) {
        float em   = (float)counts[j] * (1.0f / 131072.0f);
        float term = em * logf(em + 1e-10f);
        s += (double)term;
    }
    double l = 0.0;
#pragma unroll
    for (int j = 0; j < AGRID / 256; ++j) l += partials[j * 256 + t];
    sh[t] = s;
    sl[t] = l;
    __syncthreads();
    for (int off = 128; off > 0; off >>= 1) {
        if (t < off) { sh[t] += sh[t + off]; sl[t] += sl[t + off]; }
        __syncthreads();
    }
    if (t == 0) {
        float mm = (float)(sl[0] / 8388608.0);
        scalars[0] = mm + 0.5f * mm;         // mean1 + BETA*mean2
        scalars[1] = expf(-(float)sh[0]);    // perplexity
    }
}

// ---------------------------------------------------------------- launch
extern "C" void kernel_launch(void* const* d_in, const int* in_sizes, int n_in,
                              void* d_out, int out_size, void* d_ws, size_t ws_size,
                              hipStream_t stream)
{
    const float* z  = (const float*)d_in[0];
    const float* cb = (const float*)d_in[1];
    float* out     = (float*)d_out;
    float* zq      = out;                    // [32,64,64,64]
    float* scalars = out + ZQ_ELEM;          // loss, perplexity
    float* idx_f   = out + ZQ_ELEM + 2;      // [32,64,64] as float

    int*            counts   = (int*)d_ws;                             // 4 KB
    double*         partials = (double*)((char*)d_ws + 4096);          // 8 KB
    float*          ee       = (float*)((char*)d_ws + 12288);          // 4 KB
    unsigned short* ehi      = (unsigned short*)((char*)d_ws + 16384); // 128 KB

    hipMemsetAsync(d_ws, 0, 4096, stream);                    // zero counts
    vq_prep  <<<4,     256, 0, stream>>>(cb, ee, ehi);
    vq_argmin<<<AGRID, 256, 0, stream>>>(z, cb, ehi, ee, idx_f, counts, zq, partials);
    vq_final <<<1,     256, 0, stream>>>(counts, partials, scalars);
}

// Round 16
// 112.054 us; speedup vs baseline: 2.7993x; 1.7955x over previous
//
#include <hip/hip_runtime.h>
#include <math.h>

#define NUM_E   1024
#define ZQ_ELEM 8388608         // 32*64*64*64
#define AGRID   1024
#define QCAP    2048

typedef short bf16x8 __attribute__((ext_vector_type(8)));
typedef float f32x16 __attribute__((ext_vector_type(16)));

__device__ inline unsigned short rne_bf16(float v) {
    unsigned u = __float_as_uint(v);
    return (unsigned short)((u + 0x7FFFu + ((u >> 16) & 1u)) >> 16);  // RNE, finite-safe
}

// ---------------------------------------------------------------- prep: ee + bf16-hi B fragments
// B-frag layout for mfma_f32_32x32x16_bf16: lane l holds col j = nt*32+(l&31),
// k = kt*16 + (l>>5)*8 + i.  Packet index = (nt*4+kt)*64 + (l>>5)*32 + (j&31).
__global__ __launch_bounds__(256) void vq_prep(const float* __restrict__ cb,
                                               float* __restrict__ ee,
                                               unsigned short* __restrict__ ehi)
{
    int j = blockIdx.x * 256 + threadIdx.x;   // grid 4 -> 1024 codes
    const float* r = cb + (size_t)j * 64;
    float v[64];
#pragma unroll
    for (int k = 0; k < 64; ++k) v[k] = r[k];
    float a = 0.f;
#pragma unroll
    for (int k = 0; k < 64; ++k) a = fmaf(v[k], v[k], a);   // same chain as r1-r15
    ee[j] = a;

    int nt = j >> 5, jc = j & 31;
#pragma unroll
    for (int kt = 0; kt < 4; ++kt)
#pragma unroll
        for (int h = 0; h < 2; ++h) {
            bf16x8 vh;
#pragma unroll
            for (int i = 0; i < 8; ++i)
                vh[i] = (short)rne_bf16(v[kt * 16 + h * 8 + i]);
            *(bf16x8*)(ehi + ((size_t)(nt * 4 + kt) * 64 + h * 32 + jc) * 8) = vh;
        }
}

// exact refine of one (point, code): bit-identical to the r1-r15 passing formula.
// z read from global (zb = z + block offset), stride 4096 floats per k.
__device__ inline void refine_one(const float* zb, const float* zzs,
                                  const float* ee, const float* cb,
                                  unsigned long long* best, int pl, int j)
{
    const float4* cr = (const float4*)(cb + ((size_t)j << 6));
    float a = 0.f;
#pragma unroll
    for (int q = 0; q < 16; ++q) {
        float4 c4 = cr[q];
        a = fmaf(zb[(size_t)(4 * q + 0) * 4096 + pl], c4.x, a);
        a = fmaf(zb[(size_t)(4 * q + 1) * 4096 + pl], c4.y, a);
        a = fmaf(zb[(size_t)(4 * q + 2) * 4096 + pl], c4.z, a);
        a = fmaf(zb[(size_t)(4 * q + 3) * 4096 + pl], c4.w, a);
    }
    float t1 = zzs[pl] + ee[j];
    float d  = fmaf(-2.f, a, t1);
    unsigned long long key =
        ((unsigned long long)__float_as_uint(d) << 32) | (unsigned long long)j;
    atomicMin(best + pl, key);               // lexicographic (d, j): lowest idx on tie
}

#define LOADB(H, EV, ntv) do {                                      \
    int _b = (ntv) * 4 * 64 + lane;                                 \
    _Pragma("unroll")                                               \
    for (int _k = 0; _k < 4; ++_k) H[_k] = eh8[_b + _k * 64];       \
    EV = ee[(ntv) * 32 + (lane & 31)];                              \
} while (0)

// ---------------------------------------------------------------- argmin + quant (fused)
// Block = 128 points (2 h-rows), 256 threads = 4 waves; wave wv owns rows wv*32..wv*32+31.
// 1024 blocks -> 4 blocks/CU -> 4 waves/SIMD (the round-7 fix: TLP for latency hiding).
__global__ __launch_bounds__(256, 4) void vq_argmin(
    const float* __restrict__ z, const float* __restrict__ cb,
    const unsigned short* __restrict__ ehi, const float* __restrict__ ee,
    float* __restrict__ idx_f, int* __restrict__ counts,
    float* __restrict__ zq, double* __restrict__ partials)
{
    __shared__ float zzs[128];
    __shared__ float wp[128];                  // per-point rigorous window
    __shared__ unsigned long long best[128];
    __shared__ unsigned int queue[QCAP];       // 8 KB: (pl<<16)|j
    __shared__ unsigned int qcnt;
    __shared__ unsigned int oflow;
    __shared__ int ibuf[128];
    __shared__ double wsum[4];

    const int tid  = threadIdx.x;
    const int g    = blockIdx.x;               // 1024 blocks: (b, h-pair)
    const int lane = tid & 63, wv = tid >> 6;
    const size_t zoff = ((size_t)(g >> 5) << 18) + (size_t)((g & 31) << 7);
    const float* zb = z + zoff;
    const bf16x8* eh8 = (const bf16x8*)ehi;

    if (tid < 128) best[tid] = 0xFFFFFFFFFFFFFFFFull;
    if (tid == 0) { qcnt = 0; oflow = 0; }

    // ---- zz: exact 64-chain fmaf order (same as r1-r15), coalesced global reads
    if (tid < 128) {
        float vv[64];
#pragma unroll
        for (int k = 0; k < 64; ++k) vv[k] = zb[(size_t)k * 4096 + tid];
        float a = 0.f;
#pragma unroll
        for (int k = 0; k < 64; ++k) a = fmaf(vv[k], vv[k], a);
        zzs[tid] = a;
    }

    // ---- A-fragment (z-hi) + per-point window; one 32-row group per wave
    bf16x8 ah[4];
    {
        int h = lane >> 5;
        int pl = wv * 32 + (lane & 31);
        float s1 = 0.f, sd = 0.f;
#pragma unroll
        for (int kt = 0; kt < 4; ++kt)
#pragma unroll
            for (int i = 0; i < 8; ++i) {
                int k = kt * 16 + h * 8 + i;
                float x = zb[(size_t)k * 4096 + pl];
                unsigned short hb = rne_bf16(x);
                float hf = __uint_as_float((unsigned)hb << 16);
                ah[kt][i] = (short)hb;
                s1 += fabsf(x);
                sd += fabsf(x - hf);
            }
        s1 += __shfl_xor(s1, 32);
        sd += __shfl_xor(sd, 32);
        // W = 2*eps_data bound (x2 margin) + 4e-5 (d<->s offset roundings) + 1e-4 margin
        if (lane < 32) wp[pl] = 4.f * (s1 * 1.907e-6f + sd * 9.785e-4f) + 1.4e-4f;
    }
    __syncthreads();                           // zzs/wp visible block-wide

    float m[16];
#pragma unroll
    for (int r = 0; r < 16; ++r) m[r] = 3.4e38f;

    bf16x8 hA[4], hB[4];
    float  eA, eB;

    // ---- sweep 1: per-row min of s~ (barrier-free, ping-pong prefetch)
    LOADB(hA, eA, 0);
#pragma unroll 1
    for (int nt = 0; nt < 32; nt += 2) {
        LOADB(hB, eB, nt + 1);
        {
            f32x16 acc;
#pragma unroll
            for (int r = 0; r < 16; ++r) acc[r] = 0.f;
#pragma unroll
            for (int kt = 0; kt < 4; ++kt)
                acc = __builtin_amdgcn_mfma_f32_32x32x16_bf16(ah[kt], hA[kt], acc, 0, 0, 0);
#pragma unroll
            for (int r = 0; r < 16; ++r) m[r] = fminf(m[r], fmaf(-2.f, acc[r], eA));
        }
        if (nt + 2 < 32) LOADB(hA, eA, nt + 2);
        {
            f32x16 acc;
#pragma unroll
            for (int r = 0; r < 16; ++r) acc[r] = 0.f;
#pragma unroll
            for (int kt = 0; kt < 4; ++kt)
                acc = __builtin_amdgcn_mfma_f32_32x32x16_bf16(ah[kt], hB[kt], acc, 0, 0, 0);
#pragma unroll
            for (int r = 0; r < 16; ++r) m[r] = fminf(m[r], fmaf(-2.f, acc[r], eB));
        }
    }
    // butterfly min across 32 col-lanes, then fold per-point window -> threshold
#pragma unroll
    for (int r = 0; r < 16; ++r) {
        for (int d2 = 1; d2 <= 16; d2 <<= 1)
            m[r] = fminf(m[r], __shfl_xor(m[r], d2));
        m[r] += wp[wv * 32 + 4 * (lane >> 5) + (r & 3) + 8 * (r >> 2)];
    }

    // ---- sweep 2: recompute (bit-identical), __any-guarded enqueue; overflow -> flag
    LOADB(hA, eA, 0);
#pragma unroll 1
    for (int nt = 0; nt < 32; nt += 2) {
        LOADB(hB, eB, nt + 1);
        {
            f32x16 acc;
#pragma unroll
            for (int r = 0; r < 16; ++r) acc[r] = 0.f;
#pragma unroll
            for (int kt = 0; kt < 4; ++kt)
                acc = __builtin_amdgcn_mfma_f32_32x32x16_bf16(ah[kt], hA[kt], acc, 0, 0, 0);
            unsigned jj = (unsigned)(nt * 32 + (lane & 31));
#pragma unroll
            for (int r = 0; r < 16; ++r) {
                bool hit = fmaf(-2.f, acc[r], eA) <= m[r];
                if (__any(hit)) {
                    if (hit) {
                        int pl = wv * 32 + 4 * (lane >> 5) + (r & 3) + 8 * (r >> 2);
                        unsigned slot = atomicAdd(&qcnt, 1u);
                        if (slot < QCAP) queue[slot] = ((unsigned)pl << 16) | jj;
                        else oflow = 1;
                    }
                }
            }
        }
        if (nt + 2 < 32) LOADB(hA, eA, nt + 2);
        {
            f32x16 acc;
#pragma unroll
            for (int r = 0; r < 16; ++r) acc[r] = 0.f;
#pragma unroll
            for (int kt = 0; kt < 4; ++kt)
                acc = __builtin_amdgcn_mfma_f32_32x32x16_bf16(ah[kt], hB[kt], acc, 0, 0, 0);
            unsigned jj = (unsigned)((nt + 1) * 32 + (lane & 31));
#pragma unroll
            for (int r = 0; r < 16; ++r) {
                bool hit = fmaf(-2.f, acc[r], eB) <= m[r];
                if (__any(hit)) {
                    if (hit) {
                        int pl = wv * 32 + 4 * (lane >> 5) + (r & 3) + 8 * (r >> 2);
                        unsigned slot = atomicAdd(&qcnt, 1u);
                        if (slot < QCAP) queue[slot] = ((unsigned)pl << 16) | jj;
                        else oflow = 1;
                    }
                }
            }
        }
    }
    __syncthreads();

    // ---- exact refine (expected ~175 candidates; oflow path is a never-taken safety net)
    if (oflow) {
        if (tid < 128)
            for (int j = 0; j < NUM_E; ++j) refine_one(zb, zzs, ee, cb, best, tid, j);
    } else {
        int nq = (int)qcnt;
        for (int e = tid; e < nq; e += 256) {
            unsigned u = queue[e];
            refine_one(zb, zzs, ee, cb, best, (int)(u >> 16), (int)(u & 0xFFFFu));
        }
    }
    __syncthreads();
    if (tid < 128) {
        int bi = (int)(best[tid] & 0xFFFFFFFFull);
        ibuf[tid] = bi;
        idx_f[(size_t)g * 128 + tid] = (float)bi;
        atomicAdd(&counts[bi], 1);
    }
    __syncthreads();

    // ---- fused tail: z_q_st = fl(z + fl(q - z)), float4 stores; loss partial
    {
        int w4 = tid & 31, c8 = (tid >> 5) * 8;
        const float4* zb4 = (const float4*)zb;
        float4* zq4 = (float4*)(zq + zoff);
        size_t b0 = (size_t)ibuf[w4 * 4 + 0] << 6;
        size_t b1 = (size_t)ibuf[w4 * 4 + 1] << 6;
        size_t b2 = (size_t)ibuf[w4 * 4 + 2] << 6;
        size_t b3 = (size_t)ibuf[w4 * 4 + 3] << 6;
        double ls = 0.0;
#pragma unroll
        for (int i = 0; i < 8; ++i) {
            int c = c8 + i;
            float4 zv = zb4[(size_t)c * 1024 + w4];
            float q0 = cb[b0 + c], q1 = cb[b1 + c], q2 = cb[b2 + c], q3 = cb[b3 + c];
            float t0 = q0 - zv.x, t1 = q1 - zv.y, t2 = q2 - zv.z, t3 = q3 - zv.w;
            zq4[(size_t)c * 1024 + w4] =
                make_float4(zv.x + t0, zv.y + t1, zv.z + t2, zv.w + t3);
            ls += (double)t0 * t0 + (double)t1 * t1 + (double)t2 * t2 + (double)t3 * t3;
        }
#pragma unroll
        for (int off = 32; off > 0; off >>= 1) ls += __shfl_down(ls, off);
        if ((tid & 63) == 0) wsum[tid >> 6] = ls;
    }
    __syncthreads();
    if (tid == 0) partials[g] = wsum[0] + wsum[1] + wsum[2] + wsum[3];
}

// ---------------------------------------------------------------- scalars
__global__ __launch_bounds__(256) void vq_final(
    const int* __restrict__ counts, const double* __restrict__ partials,
    float* __restrict__ scalars)
{
    __shared__ double sh[256];
    __shared__ double sl[256];
    int t = threadIdx.x;
    double s = 0.0;
    for (int j = t; j < NUM_E; j += 256) {
        float em   = (float)counts[j] * (1.0f / 131072.0f);
        float term = em * logf(em + 1e-10f);
        s += (double)term;
    }
    double l = 0.0;
#pragma unroll
    for (int j = 0; j < AGRID / 256; ++j) l += partials[j * 256 + t];
    sh[t] = s;
    sl[t] = l;
    __syncthreads();
    for (int off = 128; off > 0; off >>= 1) {
        if (t < off) { sh[t] += sh[t + off]; sl[t] += sl[t + off]; }
        __syncthreads();
    }
    if (t == 0) {
        float mm = (float)(sl[0] / 8388608.0);
        scalars[0] = mm + 0.5f * mm;         // mean1 + BETA*mean2
        scalars[1] = expf(-(float)sh[0]);    // perplexity
    }
}

// ---------------------------------------------------------------- launch
extern "C" void kernel_launch(void* const* d_in, const int* in_sizes, int n_in,
                              void* d_out, int out_size, void* d_ws, size_t ws_size,
                              hipStream_t stream)
{
    const float* z  = (const float*)d_in[0];
    const float* cb = (const float*)d_in[1];
    float* out     = (float*)d_out;
    float* zq      = out;                    // [32,64,64,64]
    float* scalars = out + ZQ_ELEM;          // loss, perplexity
    float* idx_f   = out + ZQ_ELEM + 2;      // [32,64,64] as float

    int*            counts   = (int*)d_ws;                             // 4 KB
    double*         partials = (double*)((char*)d_ws + 4096);          // 8 KB
    float*          ee       = (float*)((char*)d_ws + 12288);          // 4 KB
    unsigned short* ehi      = (unsigned short*)((char*)d_ws + 16384); // 128 KB

    hipMemsetAsync(d_ws, 0, 4096, stream);                    // zero counts
    vq_prep  <<<4,     256, 0, stream>>>(cb, ee, ehi);
    vq_argmin<<<AGRID, 256, 0, stream>>>(z, cb, ehi, ee, idx_f, counts, zq, partials);
    vq_final <<<1,     256, 0, stream>>>(counts, partials, scalars);
}